// Round 4
// baseline (332.885 us; speedup 1.0000x reference)
//
#include <hip/hip_runtime.h>
#include <math.h>

#define R_BINS 64
#define Z_BINS 64
#define NBINS (R_BINS * Z_BINS)
#define BLOCK 512
#define WAVES_PER_BLOCK 8
#define GRID 512                           // 2 blocks/CU (80 KB LDS each)

static constexpr float DR     = 10.0f / 64.0f;   // 0.15625 (exact in fp32)
static constexpr float DZ     = 4.0f  / 64.0f;   // 0.0625  (exact in fp32)
static constexpr float INV_DR = 6.4f;
static constexpr float INV_DZ = 16.0f;

__device__ __forceinline__ void bin1(float x, float y, float z, float m,
                                     float* __restrict__ lbins) {
    const float r = sqrtf(x * x + y * y);
    const int i = (int)(r * INV_DR);              // r >= 0, trunc == floor
    const int j = (int)floorf((z + 2.0f) * INV_DZ);
    if (i < R_BINS && (unsigned)j < (unsigned)Z_BINS) {
        atomicAdd(&lbins[i * Z_BINS + j], m);
    }
}

// Async DMA global->LDS, 16 B per lane per issue. Dst is wave-uniform base
// (HW adds lane*16); src is per-lane. Completion counted in vmcnt.
__device__ __forceinline__ void g2l16(const void* g, void* l) {
    __builtin_amdgcn_global_load_lds(
        (const __attribute__((address_space(1))) unsigned int*)g,
        (__attribute__((address_space(3))) unsigned int*)l, 16, 0, 0);
}

// v5: same wave-chunked structure as the proven round-0 kernel, but staging
// through global_load_lds (async DMA, no VGPR destinations) with a
// double-buffered, counted-vmcnt pipeline. Rationale: 4 structurally
// different schedules through the VGPR-return path all pinned at 2.25 TB/s
// with VGPR_Count<=24 (compiler holds ~2 loads in flight/thread). The DMA
// path decouples in-flight read count from register pressure: 8 x 1 KB
// transfers in flight per wave, 64 KB/CU.
__global__ __launch_bounds__(BLOCK) void hist_kernel(const float4* __restrict__ pos4,
                                                     const float4* __restrict__ mass4,
                                                     float* __restrict__ gbins,
                                                     int nchunks) {
    __shared__ float  lbins[NBINS];                      // 16 KB
    __shared__ float4 stage[WAVES_PER_BLOCK][2][256];    // 64 KB (8 KB / wave)

    const int lane = threadIdx.x & 63;
    const int w    = threadIdx.x >> 6;

    for (int b = threadIdx.x; b < NBINS; b += BLOCK) lbins[b] = 0.0f;
    __syncthreads();

    const int totalWaves = GRID * WAVES_PER_BLOCK;       // 4096
    const int wid  = blockIdx.x * WAVES_PER_BLOCK + w;
    const int per  = (nchunks + totalWaves - 1) / totalWaves;   // 16 at N=16.7M
    const int c0   = wid * per;
    const int c1   = min(c0 + per, nchunks);

    // chunk c = 256 particles: 3 KB pos (3 x 1 KB DMA) + 1 KB mass (1 DMA)
    // into stage[w][c&1]: float offsets [0,768) = xyz, [768,1024) = mass.
    if (c0 < c1) {
        const float4* pb = pos4 + (size_t)192 * c0 + lane;
        float4* d = &stage[w][c0 & 1][0];
        g2l16(pb,       d);
        g2l16(pb + 64,  d + 64);
        g2l16(pb + 128, d + 128);
        g2l16(mass4 + (size_t)64 * c0 + lane, d + 192);
    }

    for (int c = c0; c < c1; ++c) {
        if (c + 1 < c1) {
            // prefetch next chunk into the other buffer, then wait for OURS
            // only (counted vmcnt: 8 outstanding -> wait to 4 = next stays
            // in flight across the compute phase).
            const float4* pb = pos4 + (size_t)192 * (c + 1) + lane;
            float4* d = &stage[w][(c + 1) & 1][0];
            g2l16(pb,       d);
            g2l16(pb + 64,  d + 64);
            g2l16(pb + 128, d + 128);
            g2l16(mass4 + (size_t)64 * (c + 1) + lane, d + 192);
            __asm__ volatile("s_waitcnt vmcnt(4)" ::: "memory");
        } else {
            __asm__ volatile("s_waitcnt vmcnt(0)" ::: "memory");
        }
        __builtin_amdgcn_sched_barrier(0);
        __builtin_amdgcn_wave_barrier();

        const float* s = (const float*)&stage[w][c & 1][0];
#pragma unroll
        for (int k = 0; k < 4; ++k) {
            const int p = (k << 6) + lane;          // stride-3 reads: gcd(3,32)=1
            bin1(s[3 * p], s[3 * p + 1], s[3 * p + 2], s[768 + p], lbins);
        }
        // write-after-read safety for the buffer this wave just consumed:
        // every ds_read's value was used by VALU before the next iteration's
        // DMA issue targets that buffer (program order + compiler lgkm waits).
        __builtin_amdgcn_wave_barrier();
    }

    __syncthreads();
    // Skip-zero atomic drain (measured free in round 0: overlaps fully).
    for (int b = threadIdx.x; b < NBINS; b += BLOCK) {
        const float v = lbins[b];
        if (v != 0.0f) atomicAdd(&gbins[b], v);
    }
}

// Tail for n % 256 != 0 (not hit at N=16777216; kept for robustness).
__global__ void tail_kernel(const float* __restrict__ pos,
                            const float* __restrict__ mass,
                            float* __restrict__ gbins,
                            int start, int n) {
    const int t = start + blockIdx.x * blockDim.x + threadIdx.x;
    if (t < n) {
        const float x = pos[3 * t], y = pos[3 * t + 1], z = pos[3 * t + 2];
        const float r = sqrtf(x * x + y * y);
        const int i = (int)(r * INV_DR);
        const int j = (int)floorf((z + 2.0f) * INV_DZ);
        if (i < R_BINS && (unsigned)j < (unsigned)Z_BINS) {
            atomicAdd(&gbins[i * Z_BINS + j], mass[t]);
        }
    }
}

__global__ __launch_bounds__(256) void finalize_kernel(const float* __restrict__ gbins,
                                                       float* __restrict__ out) {
    const int idx = blockIdx.x * blockDim.x + threadIdx.x;
    if (idx < NBINS) {
        const int i = idx / Z_BINS;
        const float r0 = (float)i * DR;
        const float r1 = (float)(i + 1) * DR;
        const float area = (float)M_PI * (r1 * r1 - r0 * r0);
        out[idx] = gbins[idx] / (area * DZ);
    }
}

extern "C" void kernel_launch(void* const* d_in, const int* in_sizes, int n_in,
                              void* d_out, int out_size, void* d_ws, size_t ws_size,
                              hipStream_t stream) {
    const float* positions = (const float*)d_in[0];  // (N,3) interleaved xyz
    const float* masses    = (const float*)d_in[1];  // (N,)
    float* out   = (float*)d_out;                    // (64*64,)
    float* gbins = (float*)d_ws;                     // 16 KB accumulator

    const int n = in_sizes[1];
    const int nchunks = n / 256;
    const int rem = n - nchunks * 256;

    // d_ws is re-poisoned to 0xAA before every timed call — zero it.
    hipMemsetAsync(gbins, 0, NBINS * sizeof(float), stream);

    hist_kernel<<<GRID, BLOCK, 0, stream>>>((const float4*)positions,
                                            (const float4*)masses,
                                            gbins, nchunks);
    if (rem > 0) {
        tail_kernel<<<(rem + 255) / 256, 256, 0, stream>>>(positions, masses,
                                                           gbins, nchunks * 256, n);
    }
    finalize_kernel<<<(NBINS + 255) / 256, 256, 0, stream>>>(gbins, out);
}